// Round 4
// baseline (216.440 us; speedup 1.0000x reference)
//
#include <hip/hip_runtime.h>
#include <math.h>

#define B_ 4
#define C_ 128
#define CI_ 64
#define H_ 96
#define W_ 96
#define HW_ (H_*W_)      // 9216
#define NP_ 2304         // 48*48
#define GROUPS_ 32
#define EPS_ 1e-5f

typedef _Float16 f16x8 __attribute__((ext_vector_type(8)));
typedef _Float16 f16x2 __attribute__((ext_vector_type(2)));
typedef __attribute__((ext_vector_type(4))) float f32x4;

__device__ inline f32x4 mfma16h(f16x8 a, f16x8 b, f32x4 c) {
    return __builtin_amdgcn_mfma_f32_16x16x32_f16(a, b, c, 0, 0, 0);
}
__device__ inline float h2f(unsigned short s) {
    return (float)__builtin_bit_cast(_Float16, s);
}
__device__ inline unsigned pk_f16(float a, float b) {     // pack 2 f32 -> 2 f16 (RTZ)
    return __builtin_bit_cast(unsigned, __builtin_amdgcn_cvt_pkrtz(a, b));
}

// ---------------------------------------------------------------------------
// Kernel 1: fused 3-way 1x1 conv projections -> fp16 [b][n][ci]
// ---------------------------------------------------------------------------
__global__ __launch_bounds__(256) void proj_kernel(
    const float* __restrict__ x,
    const float* __restrict__ w_theta, const float* __restrict__ b_theta,
    const float* __restrict__ w_phi,   const float* __restrict__ b_phi,
    const float* __restrict__ w_g,     const float* __restrict__ b_g,
    unsigned short* __restrict__ Qo, unsigned short* __restrict__ phiF,
    unsigned short* __restrict__ gF)
{
    __shared__ float xs[C_ * 32];   // xs[c*32 + pix]
    __shared__ float ws[C_ * 68];   // ws[c*68 + ci]
    const int t    = threadIdx.x;
    const int tile = blockIdx.x;
    const int b    = blockIdx.y;
    const int mat  = blockIdx.z;
    const float* wsel = (mat == 0) ? w_theta : (mat == 1) ? w_phi : w_g;
    const float* bsel = (mat == 0) ? b_theta : (mat == 1) ? b_phi : b_g;
    unsigned short* osel = (mat == 0) ? Qo : (mat == 1) ? phiF : gF;
    const int n0 = tile * 32;

    {
        const int pix = t & 31;
        const int c0  = t >> 5;
        const float* xb = x + (size_t)b * C_ * HW_ + n0 + pix;
        for (int c = c0; c < C_; c += 8)
            xs[c * 32 + pix] = xb[(size_t)c * HW_];
    }
    for (int j = t; j < CI_ * C_; j += 256)
        ws[(j & 127) * 68 + (j >> 7)] = wsel[j];
    __syncthreads();

    const int tp = (t & 7) * 4;
    const int tc = (t >> 3) * 2;
    float acc[4][2] = {};
    #pragma unroll 4
    for (int c = 0; c < C_; ++c) {
        const float4 xv = *(const float4*)&xs[c * 32 + tp];
        const float2 wv = *(const float2*)&ws[c * 68 + tc];
        const float xa[4] = {xv.x, xv.y, xv.z, xv.w};
        #pragma unroll
        for (int i = 0; i < 4; ++i) {
            acc[i][0] += xa[i] * wv.x;
            acc[i][1] += xa[i] * wv.y;
        }
    }
    const float2 bb = *(const float2*)&bsel[tc];
    #pragma unroll
    for (int i = 0; i < 4; ++i) {
        f16x2 hv = { (_Float16)(acc[i][0] + bb.x), (_Float16)(acc[i][1] + bb.y) };
        *(f16x2*)&osel[((size_t)b * HW_ + n0 + tp + i) * CI_ + tc] = hv;
    }
}

// ---------------------------------------------------------------------------
// Kernel 2: 2x2 maxpool (fp16 in/out, exact). K stays [b][m][ci]; V -> [b][ci][m].
// ---------------------------------------------------------------------------
__global__ __launch_bounds__(256) void pool_kernel(
    const unsigned short* __restrict__ phiF, const unsigned short* __restrict__ gF,
    unsigned short* __restrict__ Ko, unsigned short* __restrict__ Vt)
{
    const int t   = threadIdx.x;
    const int b   = blockIdx.y;
    const int mat = blockIdx.z;                 // 0 -> K, 1 -> V^T
    const int idx = blockIdx.x * 256 + t;       // 0..147455
    int m, ci;
    if (mat == 0) { m = idx >> 6; ci = idx & 63; }
    else          { ci = idx / NP_; m = idx - ci * NP_; }
    const int ph = m / 48, pw = m % 48;
    const int n00 = (ph * 2) * W_ + pw * 2;
    const unsigned short* src = mat ? gF : phiF;
    const unsigned short* p = src + ((size_t)b * HW_ + n00) * CI_ + ci;
    float v = fmaxf(fmaxf(h2f(p[0]), h2f(p[CI_])),
                    fmaxf(h2f(p[(size_t)W_ * CI_]), h2f(p[(size_t)(W_ + 1) * CI_])));
    unsigned short r = __builtin_bit_cast(unsigned short, (_Float16)v); // exact
    if (mat == 0) Ko[((size_t)b * NP_ + m) * CI_ + ci] = r;
    else          Vt[((size_t)b * CI_ + ci) * NP_ + m] = r;
}

// ---------------------------------------------------------------------------
// Kernel 3: fp16 MFMA flash attention.
// Block = 3 waves x 16 q-rows (48 rows). Grid 192x4 = 768 blocks = 3/CU exact.
// KV tile = 64. Swapped QK^T. K_lds[k][d], V_lds[d][k] XOR-swizzled 128B rows.
// Staging is reg-split (issue-early / write-late) to hide HBM latency.
// ---------------------------------------------------------------------------
__global__ __launch_bounds__(192) void attn_kernel(
    const unsigned short* __restrict__ Qg, const unsigned short* __restrict__ Kg,
    const unsigned short* __restrict__ Vt, float* __restrict__ Yg)
{
    __shared__ unsigned char Ks[64 * 128];       // 8 KB, swizzled [k][d]
    __shared__ unsigned char Vs[64 * 128];       // 8 KB, swizzled [d][k]
    __shared__ unsigned char Ps[3][16 * 144];    // per-wave P, 144B row stride

    const int t    = threadIdx.x;
    const int wv   = t >> 6;
    const int lane = t & 63;
    const int lr   = lane & 15;
    const int lg   = lane >> 4;
    const int b    = blockIdx.y;
    const int q0   = blockIdx.x * 48 + wv * 16;

    // Q fragments in registers: u in {0,1} k-steps of 32
    f16x8 qf[2];
    #pragma unroll
    for (int u = 0; u < 2; ++u)
        qf[u] = *(const f16x8*)(Qg + ((size_t)b * HW_ + q0 + lr) * CI_ + u * 32 + lg * 8);

    f32x4 o_acc[4];
    #pragma unroll
    for (int dt = 0; dt < 4; ++dt) o_acc[dt] = (f32x4){0.f, 0.f, 0.f, 0.f};
    float mrun = -1e30f, lrun = 0.f;

    // staging: 512 16B-chunks per matrix, 192 threads -> 2 or 3 each
    float4 kreg[3], vreg[3];
    const int nch = (t < 128) ? 3 : 2;

#define LOAD_TILE(KV0)                                                          \
    {                                                                           \
        _Pragma("unroll")                                                       \
        for (int i = 0; i < 3; ++i) if (i < nch) {                              \
            const int idx = t + 192 * i;                                        \
            const int row = idx >> 3, ch = idx & 7;                             \
            kreg[i] = *(const float4*)(Kg + ((size_t)b * NP_ + (KV0) + row) * CI_ + ch * 8); \
            vreg[i] = *(const float4*)(Vt + ((size_t)b * CI_ + row) * NP_ + (KV0) + ch * 8); \
        }                                                                       \
    }
#define WRITE_TILE()                                                            \
    {                                                                           \
        _Pragma("unroll")                                                       \
        for (int i = 0; i < 3; ++i) if (i < nch) {                              \
            const int idx = t + 192 * i;                                        \
            const int row = idx >> 3, ch = idx & 7;                             \
            const int soff = row * 128 + ((ch * 16) ^ ((row & 7) << 4));        \
            *(float4*)&Ks[soff] = kreg[i];                                      \
            *(float4*)&Vs[soff] = vreg[i];                                      \
        }                                                                       \
    }

    LOAD_TILE(0);
    WRITE_TILE();
    __syncthreads();

    for (int kt = 0; kt < NP_ / 64; ++kt) {      // 36 KV tiles
        if (kt + 1 < NP_ / 64) LOAD_TILE((kt + 1) * 64);   // async issue

        // ---- S^T = K * Q^T : lane holds S[k = 16*kt4 + 4*lg + r][q = lr]
        f32x4 s[4];
        #pragma unroll
        for (int kt4 = 0; kt4 < 4; ++kt4) s[kt4] = (f32x4){0.f, 0.f, 0.f, 0.f};
        __builtin_amdgcn_s_setprio(1);
        #pragma unroll
        for (int u = 0; u < 2; ++u)
            #pragma unroll
            for (int kt4 = 0; kt4 < 4; ++kt4) {
                f16x8 kf = *(const f16x8*)&Ks[(kt4 * 16 + lr) * 128
                               + ((64 * u + 16 * lg) ^ ((lr & 7) << 4))];
                s[kt4] = mfma16h(kf, qf[u], s[kt4]);
            }
        __builtin_amdgcn_s_setprio(0);

        // ---- online softmax (per q-row = lr; reduce over lg via shfl_xor)
        float tmax = -1e30f;
        #pragma unroll
        for (int kt4 = 0; kt4 < 4; ++kt4)
            #pragma unroll
            for (int r = 0; r < 4; ++r) tmax = fmaxf(tmax, s[kt4][r]);
        tmax = fmaxf(tmax, __shfl_xor(tmax, 16));
        tmax = fmaxf(tmax, __shfl_xor(tmax, 32));
        const float mnew = fmaxf(mrun, tmax);

        float pv[16];
        float tsum = 0.f;
        #pragma unroll
        for (int kt4 = 0; kt4 < 4; ++kt4)
            #pragma unroll
            for (int r = 0; r < 4; ++r) {
                const float e = __expf(s[kt4][r] - mnew);
                pv[kt4 * 4 + r] = e;
                tsum += e;
            }
        tsum += __shfl_xor(tsum, 16);
        tsum += __shfl_xor(tsum, 32);

        const float scale = __expf(mrun - mnew);
        lrun = lrun * scale + tsum;
        mrun = mnew;

        // rescale O (lane holds rows q = 4*lg + r2, col = lr)
        #pragma unroll
        for (int r2 = 0; r2 < 4; ++r2) {
            const float sc = __shfl(scale, 4 * lg + r2);
            #pragma unroll
            for (int dt = 0; dt < 4; ++dt) o_acc[dt][r2] *= sc;
        }

        // ---- P -> LDS (fp16, PV A-fragment layout [q][k], 144B stride)
        #pragma unroll
        for (int kt4 = 0; kt4 < 4; ++kt4) {
            uint2 pk = { pk_f16(pv[kt4 * 4 + 0], pv[kt4 * 4 + 1]),
                         pk_f16(pv[kt4 * 4 + 2], pv[kt4 * 4 + 3]) };
            *(uint2*)&Ps[wv][lr * 144 + kt4 * 32 + lg * 8] = pk;
        }

        // ---- O += P * V
        __builtin_amdgcn_s_setprio(1);
        #pragma unroll
        for (int u = 0; u < 2; ++u) {
            f16x8 pf = *(const f16x8*)&Ps[wv][lr * 144 + 64 * u + 16 * lg];
            #pragma unroll
            for (int dt = 0; dt < 4; ++dt) {
                f16x8 vf = *(const f16x8*)&Vs[(dt * 16 + lr) * 128
                               + ((64 * u + 16 * lg) ^ ((lr & 7) << 4))];
                o_acc[dt] = mfma16h(pf, vf, o_acc[dt]);
            }
        }
        __builtin_amdgcn_s_setprio(0);

        __syncthreads();                         // all reads of Ks/Vs done
        if (kt + 1 < NP_ / 64) WRITE_TILE();     // write-late (waits vmcnt)
        __syncthreads();
    }

    // ---- finalize: divide by l, store Y[b][n][ci] fp32
    #pragma unroll
    for (int r2 = 0; r2 < 4; ++r2) {
        const float inv = 1.0f / __shfl(lrun, 4 * lg + r2);
        const int q = q0 + 4 * lg + r2;
        float* yp = Yg + ((size_t)b * HW_ + q) * CI_ + lr;
        #pragma unroll
        for (int dt = 0; dt < 4; ++dt)
            yp[dt * 16] = o_acc[dt][r2] * inv;
    }
#undef LOAD_TILE
#undef WRITE_TILE
}

// ---------------------------------------------------------------------------
// Kernel 4: 1x1 conv back to 128 channels (fp32).
// ---------------------------------------------------------------------------
__global__ __launch_bounds__(256) void conv2_kernel(
    const float* __restrict__ Yg, const float* __restrict__ wW,
    const float* __restrict__ bW, float* __restrict__ Zg)
{
    __shared__ float ys[CI_ * 68];
    __shared__ float ws2[CI_ * 132];
    const int t  = threadIdx.x;
    const int b  = blockIdx.y;
    const int n0 = blockIdx.x * 64;

    const float* ybase = Yg + ((size_t)b * HW_ + n0) * CI_;
    for (int j = t; j < 64 * CI_; j += 256)
        ys[(j & 63) * 68 + (j >> 6)] = ybase[j];
    for (int j = t; j < C_ * CI_; j += 256)
        ws2[(j & 63) * 132 + (j >> 6)] = wW[j];
    __syncthreads();

    const int tp = (t & 15) * 4;
    const int to = (t >> 4) * 8;
    float acc[4][8] = {};
    #pragma unroll 2
    for (int ci = 0; ci < CI_; ++ci) {
        const float4 yv  = *(const float4*)&ys[ci * 68 + tp];
        const float4 wv0 = *(const float4*)&ws2[ci * 132 + to];
        const float4 wv1 = *(const float4*)&ws2[ci * 132 + to + 4];
        const float ya[4] = {yv.x, yv.y, yv.z, yv.w};
        const float wa[8] = {wv0.x, wv0.y, wv0.z, wv0.w, wv1.x, wv1.y, wv1.z, wv1.w};
        #pragma unroll
        for (int i = 0; i < 4; ++i)
            #pragma unroll
            for (int j = 0; j < 8; ++j)
                acc[i][j] += ya[i] * wa[j];
    }
    #pragma unroll
    for (int j = 0; j < 8; ++j) {
        const int o = to + j;
        const float bb = bW[o];
        float* zp = Zg + ((size_t)b * C_ + o) * HW_ + n0 + tp;
        float4 v = { acc[0][j] + bb, acc[1][j] + bb, acc[2][j] + bb, acc[3][j] + bb };
        *(float4*)zp = v;
    }
}

// ---------------------------------------------------------------------------
// Kernel 5: GroupNorm stats (deterministic).
// ---------------------------------------------------------------------------
__global__ __launch_bounds__(256) void stats_kernel(
    const float* __restrict__ Zg, float* __restrict__ stats)
{
    const int t  = threadIdx.x;
    const int gr = blockIdx.x;
    const int b  = blockIdx.y;
    const float4* zp = (const float4*)(Zg + ((size_t)b * C_ + gr * 4) * HW_);
    float s = 0.f, ss = 0.f;
    for (int i = t; i < HW_; i += 256) {
        const float4 v = zp[i];
        s  += v.x + v.y + v.z + v.w;
        ss += v.x*v.x + v.y*v.y + v.z*v.z + v.w*v.w;
    }
    __shared__ float rs[256], rq[256];
    rs[t] = s; rq[t] = ss;
    __syncthreads();
    for (int off = 128; off > 0; off >>= 1) {
        if (t < off) { rs[t] += rs[t + off]; rq[t] += rq[t + off]; }
        __syncthreads();
    }
    if (t == 0) {
        const float invn = 1.0f / (4 * HW_);
        const float mean = rs[0] * invn;
        const float var  = rq[0] * invn - mean * mean;
        stats[((size_t)b * GROUPS_ + gr) * 2 + 0] = mean;
        stats[((size_t)b * GROUPS_ + gr) * 2 + 1] = rsqrtf(var + EPS_);
    }
}

// ---------------------------------------------------------------------------
// Kernel 6: normalize + affine + residual.
// ---------------------------------------------------------------------------
__global__ __launch_bounds__(256) void final_kernel(
    const float* __restrict__ Zg, const float* __restrict__ xg,
    const float* __restrict__ stats, const float* __restrict__ gnw,
    const float* __restrict__ gnb, float* __restrict__ out)
{
    const size_t i4  = (size_t)blockIdx.x * 256 + threadIdx.x;
    const size_t idx = i4 * 4;
    const int bc = (int)(i4 / (HW_ / 4));
    const int c  = bc & 127;
    const int b  = bc >> 7;
    const int g  = c >> 2;
    const float mean = stats[((size_t)b * GROUPS_ + g) * 2 + 0];
    const float rstd = stats[((size_t)b * GROUPS_ + g) * 2 + 1];
    const float sc = rstd * gnw[c];
    const float sh = gnb[c] - mean * sc;
    const float4 z  = *(const float4*)(Zg + idx);
    const float4 xv = *(const float4*)(xg + idx);
    float4 o;
    o.x = z.x * sc + sh + xv.x;
    o.y = z.y * sc + sh + xv.y;
    o.z = z.z * sc + sh + xv.z;
    o.w = z.w * sc + sh + xv.w;
    *(float4*)(out + idx) = o;
}

// ---------------------------------------------------------------------------
extern "C" void kernel_launch(void* const* d_in, const int* in_sizes, int n_in,
                              void* d_out, int out_size, void* d_ws, size_t ws_size,
                              hipStream_t stream)
{
    const float* x       = (const float*)d_in[0];
    const float* w_theta = (const float*)d_in[1];
    const float* b_theta = (const float*)d_in[2];
    const float* w_phi   = (const float*)d_in[3];
    const float* b_phi   = (const float*)d_in[4];
    const float* w_g     = (const float*)d_in[5];
    const float* b_g     = (const float*)d_in[6];
    const float* w_W     = (const float*)d_in[7];
    const float* b_W     = (const float*)d_in[8];
    const float* gn_w    = (const float*)d_in[9];
    const float* gn_b    = (const float*)d_in[10];
    float* out = (float*)d_out;
    char* wsb  = (char*)d_ws;

    // workspace layout (bytes)
    unsigned short* Q    = (unsigned short*)(wsb);             //  4,718,592
    unsigned short* K    = (unsigned short*)(wsb +  4718592);  //  1,179,648
    unsigned short* Vt   = (unsigned short*)(wsb +  5898240);  //  1,179,648
    unsigned short* phiF = (unsigned short*)(wsb +  7077888);  //  4,718,592
    unsigned short* gF   = (unsigned short*)(wsb + 11796480);  //  4,718,592
    float* Y             = (float*)(wsb +  7077888);           //  9,437,184 (aliases phiF+gF, dead after pool)
    float* Z             = (float*)(wsb + 16515072);           // 18,874,368
    float* stats         = (float*)(wsb + 35389440);           //  1 KB

    proj_kernel <<<dim3(HW_ / 32, B_, 3), 256, 0, stream>>>(
        x, w_theta, b_theta, w_phi, b_phi, w_g, b_g, Q, phiF, gF);
    pool_kernel <<<dim3(NP_ * CI_ / 256, B_, 2), 256, 0, stream>>>(phiF, gF, K, Vt);
    attn_kernel <<<dim3(HW_ / 48, B_), 192, 0, stream>>>(Q, K, Vt, Y);
    conv2_kernel<<<dim3(HW_ / 64, B_), 256, 0, stream>>>(Y, w_W, b_W, Z);
    stats_kernel<<<dim3(GROUPS_, B_), 256, 0, stream>>>(Z, stats);
    final_kernel<<<dim3((B_ * C_ * HW_) / 1024, 1), 256, 0, stream>>>(
        Z, x, stats, gn_w, gn_b, out);
}

// Round 5
// 179.066 us; speedup vs baseline: 1.2087x; 1.2087x over previous
//
#include <hip/hip_runtime.h>
#include <math.h>

#define B_ 4
#define C_ 128
#define CI_ 64
#define H_ 96
#define W_ 96
#define HW_ (H_*W_)      // 9216
#define NP_ 2304         // 48*48
#define GROUPS_ 32
#define EPS_ 1e-5f

typedef _Float16 f16x8 __attribute__((ext_vector_type(8)));
typedef _Float16 f16x2 __attribute__((ext_vector_type(2)));
typedef __attribute__((ext_vector_type(4))) float f32x4;

__device__ inline f32x4 mfma16h(f16x8 a, f16x8 b, f32x4 c) {
    return __builtin_amdgcn_mfma_f32_16x16x32_f16(a, b, c, 0, 0, 0);
}
__device__ inline float h2f(unsigned short s) {
    return (float)__builtin_bit_cast(_Float16, s);
}
__device__ inline unsigned pk_f16(float a, float b) {     // pack 2 f32 -> 2 f16 (RTZ)
    return __builtin_bit_cast(unsigned, __builtin_amdgcn_cvt_pkrtz(a, b));
}

// ---------------------------------------------------------------------------
// Kernel 1: fused 3-way 1x1 conv projections -> fp16 [b][n][ci]
// ---------------------------------------------------------------------------
__global__ __launch_bounds__(256) void proj_kernel(
    const float* __restrict__ x,
    const float* __restrict__ w_theta, const float* __restrict__ b_theta,
    const float* __restrict__ w_phi,   const float* __restrict__ b_phi,
    const float* __restrict__ w_g,     const float* __restrict__ b_g,
    unsigned short* __restrict__ Qo, unsigned short* __restrict__ phiF,
    unsigned short* __restrict__ gF)
{
    __shared__ float xs[C_ * 32];   // xs[c*32 + pix]
    __shared__ float ws[C_ * 68];   // ws[c*68 + ci]
    const int t    = threadIdx.x;
    const int tile = blockIdx.x;
    const int b    = blockIdx.y;
    const int mat  = blockIdx.z;
    const float* wsel = (mat == 0) ? w_theta : (mat == 1) ? w_phi : w_g;
    const float* bsel = (mat == 0) ? b_theta : (mat == 1) ? b_phi : b_g;
    unsigned short* osel = (mat == 0) ? Qo : (mat == 1) ? phiF : gF;
    const int n0 = tile * 32;

    {
        const int pix = t & 31;
        const int c0  = t >> 5;
        const float* xb = x + (size_t)b * C_ * HW_ + n0 + pix;
        for (int c = c0; c < C_; c += 8)
            xs[c * 32 + pix] = xb[(size_t)c * HW_];
    }
    for (int j = t; j < CI_ * C_; j += 256)
        ws[(j & 127) * 68 + (j >> 7)] = wsel[j];
    __syncthreads();

    const int tp = (t & 7) * 4;
    const int tc = (t >> 3) * 2;
    float acc[4][2] = {};
    #pragma unroll 4
    for (int c = 0; c < C_; ++c) {
        const float4 xv = *(const float4*)&xs[c * 32 + tp];
        const float2 wv = *(const float2*)&ws[c * 68 + tc];
        const float xa[4] = {xv.x, xv.y, xv.z, xv.w};
        #pragma unroll
        for (int i = 0; i < 4; ++i) {
            acc[i][0] += xa[i] * wv.x;
            acc[i][1] += xa[i] * wv.y;
        }
    }
    const float2 bb = *(const float2*)&bsel[tc];
    #pragma unroll
    for (int i = 0; i < 4; ++i) {
        f16x2 hv = { (_Float16)(acc[i][0] + bb.x), (_Float16)(acc[i][1] + bb.y) };
        *(f16x2*)&osel[((size_t)b * HW_ + n0 + tp + i) * CI_ + tc] = hv;
    }
}

// ---------------------------------------------------------------------------
// Kernel 2: 2x2 maxpool (fp16 in/out, exact). K stays [b][m][ci]; V -> [b][ci][m].
// ---------------------------------------------------------------------------
__global__ __launch_bounds__(256) void pool_kernel(
    const unsigned short* __restrict__ phiF, const unsigned short* __restrict__ gF,
    unsigned short* __restrict__ Ko, unsigned short* __restrict__ Vt)
{
    const int t   = threadIdx.x;
    const int b   = blockIdx.y;
    const int mat = blockIdx.z;                 // 0 -> K, 1 -> V^T
    const int idx = blockIdx.x * 256 + t;       // 0..147455
    int m, ci;
    if (mat == 0) { m = idx >> 6; ci = idx & 63; }
    else          { ci = idx / NP_; m = idx - ci * NP_; }
    const int ph = m / 48, pw = m % 48;
    const int n00 = (ph * 2) * W_ + pw * 2;
    const unsigned short* src = mat ? gF : phiF;
    const unsigned short* p = src + ((size_t)b * HW_ + n00) * CI_ + ci;
    float v = fmaxf(fmaxf(h2f(p[0]), h2f(p[CI_])),
                    fmaxf(h2f(p[(size_t)W_ * CI_]), h2f(p[(size_t)(W_ + 1) * CI_])));
    unsigned short r = __builtin_bit_cast(unsigned short, (_Float16)v); // exact
    if (mat == 0) Ko[((size_t)b * NP_ + m) * CI_ + ci] = r;
    else          Vt[((size_t)b * CI_ + ci) * NP_ + m] = r;
}

// ---------------------------------------------------------------------------
// Kernel 3: fp16 MFMA flash attention — wave-independent, barrier-free.
// 1 wave/block, 32 q-rows/wave. K/V read DIRECTLY from global (L1/L2-resident:
// K,V = 288 KB/batch each). K double-buffered in regs (prefetch next tile at
// body start — no barriers for the scheduler to sink loads across). Only LDS:
// tiny per-wave P-repack buffer (wave-internal, no syncthreads anywhere).
// Defer-max (THR=8) skips the O-rescale on most tiles.
// ---------------------------------------------------------------------------
__global__ __launch_bounds__(64, 2) void attn_kernel(
    const unsigned short* __restrict__ Qg, const unsigned short* __restrict__ Kg,
    const unsigned short* __restrict__ Vt, float* __restrict__ Yg)
{
    __shared__ unsigned char Ps[16 * 144];       // per-wave P, 144B row stride

    const int lane = threadIdx.x;
    const int lr   = lane & 15;
    const int lg   = lane >> 4;
    const int b    = blockIdx.y;
    const int q0   = blockIdx.x * 32;

    const unsigned short* Kb = Kg + (size_t)b * NP_ * CI_;
    const unsigned short* Vb = Vt + (size_t)b * CI_ * NP_;

    // Q fragments in registers: qs in {0,1} sub-tiles, u in {0,1} k-steps
    f16x8 qf[2][2];
    #pragma unroll
    for (int qs = 0; qs < 2; ++qs)
        #pragma unroll
        for (int u = 0; u < 2; ++u)
            qf[qs][u] = *(const f16x8*)(Qg
                + ((size_t)b * HW_ + q0 + qs * 16 + lr) * CI_ + u * 32 + lg * 8);

    f32x4 o_acc[2][4];
    #pragma unroll
    for (int qs = 0; qs < 2; ++qs)
        #pragma unroll
        for (int dt = 0; dt < 4; ++dt)
            o_acc[qs][dt] = (f32x4){0.f, 0.f, 0.f, 0.f};
    float mrun[2] = {-1e30f, -1e30f};
    float lrun[2] = {0.f, 0.f};

    f16x8 kA[8], kB[8], vcur[8];

#define LOADK(DST, KV0)                                                         \
    {                                                                           \
        _Pragma("unroll")                                                       \
        for (int u = 0; u < 2; ++u)                                             \
            _Pragma("unroll")                                                   \
            for (int k4 = 0; k4 < 4; ++k4)                                      \
                DST[u * 4 + k4] = *(const f16x8*)(Kb                            \
                    + ((KV0) + k4 * 16 + lr) * CI_ + u * 32 + lg * 8);          \
    }
#define LOADV(DST, KV0)                                                         \
    {                                                                           \
        _Pragma("unroll")                                                       \
        for (int u = 0; u < 2; ++u)                                             \
            _Pragma("unroll")                                                   \
            for (int dt = 0; dt < 4; ++dt)                                      \
                DST[u * 4 + dt] = *(const f16x8*)(Vb                            \
                    + (dt * 16 + lr) * NP_ + (KV0) + u * 32 + lg * 8);          \
    }

    auto body = [&](const f16x8 (&kc)[8], f16x8 (&kn)[8], int T, bool pf) {
        const int kv0 = T * 64;
        LOADV(vcur, kv0);                       // consumed at PV (latency hidden)
        if (pf) LOADK(kn, kv0 + 64);            // next-tile K prefetch

        #pragma unroll
        for (int qs = 0; qs < 2; ++qs) {
            // ---- S^T = K * Q^T : lane holds S[k = 16*k4 + 4*lg + r][q = lr]
            f32x4 s[4];
            #pragma unroll
            for (int k4 = 0; k4 < 4; ++k4) s[k4] = (f32x4){0.f, 0.f, 0.f, 0.f};
            __builtin_amdgcn_s_setprio(1);
            #pragma unroll
            for (int u = 0; u < 2; ++u)
                #pragma unroll
                for (int k4 = 0; k4 < 4; ++k4)
                    s[k4] = mfma16h(kc[u * 4 + k4], qf[qs][u], s[k4]);
            __builtin_amdgcn_s_setprio(0);

            // ---- online softmax with defer-max (THR=8)
            float tmax = -1e30f;
            #pragma unroll
            for (int k4 = 0; k4 < 4; ++k4)
                tmax = fmaxf(tmax, fmaxf(fmaxf(s[k4][0], s[k4][1]),
                                         fmaxf(s[k4][2], s[k4][3])));
            tmax = fmaxf(tmax, __shfl_xor(tmax, 16));
            tmax = fmaxf(tmax, __shfl_xor(tmax, 32));

            if (!__all(tmax <= mrun[qs] + 8.0f)) {
                const float mnew = fmaxf(mrun[qs], tmax);
                const float sc = __expf(mrun[qs] - mnew);
                lrun[qs] *= sc;
                #pragma unroll
                for (int r2 = 0; r2 < 4; ++r2) {
                    const float scb = __shfl(sc, 4 * lg + r2);
                    #pragma unroll
                    for (int dt = 0; dt < 4; ++dt) o_acc[qs][dt][r2] *= scb;
                }
                mrun[qs] = mnew;
            }

            float pv[16];
            float tsum = 0.f;
            #pragma unroll
            for (int k4 = 0; k4 < 4; ++k4)
                #pragma unroll
                for (int r = 0; r < 4; ++r) {
                    const float e = __expf(s[k4][r] - mrun[qs]);
                    pv[k4 * 4 + r] = e;
                    tsum += e;
                }
            tsum += __shfl_xor(tsum, 16);
            tsum += __shfl_xor(tsum, 32);
            lrun[qs] += tsum;

            // ---- P -> LDS (fp16, PV A-fragment layout [q][k], 144B stride)
            #pragma unroll
            for (int k4 = 0; k4 < 4; ++k4) {
                uint2 pk = { pk_f16(pv[k4 * 4 + 0], pv[k4 * 4 + 1]),
                             pk_f16(pv[k4 * 4 + 2], pv[k4 * 4 + 3]) };
                *(uint2*)&Ps[lr * 144 + k4 * 32 + lg * 8] = pk;
            }

            // ---- O += P * V
            #pragma unroll
            for (int u = 0; u < 2; ++u) {
                f16x8 pfr = *(const f16x8*)&Ps[lr * 144 + 64 * u + 16 * lg];
                __builtin_amdgcn_s_setprio(1);
                #pragma unroll
                for (int dt = 0; dt < 4; ++dt)
                    o_acc[qs][dt] = mfma16h(pfr, vcur[u * 4 + dt], o_acc[qs][dt]);
                __builtin_amdgcn_s_setprio(0);
            }
        }
    };

    LOADK(kA, 0);
    for (int kt = 0; kt < NP_ / 64; kt += 2) {   // 36 tiles, unrolled by 2
        body(kA, kB, kt, true);
        body(kB, kA, kt + 1, kt + 2 < NP_ / 64);
    }

    // ---- finalize: divide by l, store Y[b][n][ci] fp32
    #pragma unroll
    for (int qs = 0; qs < 2; ++qs)
        #pragma unroll
        for (int r2 = 0; r2 < 4; ++r2) {
            const float inv = 1.0f / __shfl(lrun[qs], 4 * lg + r2);
            const int q = q0 + qs * 16 + 4 * lg + r2;
            float* yp = Yg + ((size_t)b * HW_ + q) * CI_ + lr;
            #pragma unroll
            for (int dt = 0; dt < 4; ++dt)
                yp[dt * 16] = o_acc[qs][dt][r2] * inv;
        }
#undef LOADK
#undef LOADV
}

// ---------------------------------------------------------------------------
// Kernel 4: 1x1 conv back to 128 channels (fp32).
// ---------------------------------------------------------------------------
__global__ __launch_bounds__(256) void conv2_kernel(
    const float* __restrict__ Yg, const float* __restrict__ wW,
    const float* __restrict__ bW, float* __restrict__ Zg)
{
    __shared__ float ys[CI_ * 68];
    __shared__ float ws2[CI_ * 132];
    const int t  = threadIdx.x;
    const int b  = blockIdx.y;
    const int n0 = blockIdx.x * 64;

    const float* ybase = Yg + ((size_t)b * HW_ + n0) * CI_;
    for (int j = t; j < 64 * CI_; j += 256)
        ys[(j & 63) * 68 + (j >> 6)] = ybase[j];
    for (int j = t; j < C_ * CI_; j += 256)
        ws2[(j & 63) * 132 + (j >> 6)] = wW[j];
    __syncthreads();

    const int tp = (t & 15) * 4;
    const int to = (t >> 4) * 8;
    float acc[4][8] = {};
    #pragma unroll 2
    for (int ci = 0; ci < CI_; ++ci) {
        const float4 yv  = *(const float4*)&ys[ci * 68 + tp];
        const float4 wv0 = *(const float4*)&ws2[ci * 132 + to];
        const float4 wv1 = *(const float4*)&ws2[ci * 132 + to + 4];
        const float ya[4] = {yv.x, yv.y, yv.z, yv.w};
        const float wa[8] = {wv0.x, wv0.y, wv0.z, wv0.w, wv1.x, wv1.y, wv1.z, wv1.w};
        #pragma unroll
        for (int i = 0; i < 4; ++i)
            #pragma unroll
            for (int j = 0; j < 8; ++j)
                acc[i][j] += ya[i] * wa[j];
    }
    #pragma unroll
    for (int j = 0; j < 8; ++j) {
        const int o = to + j;
        const float bb = bW[o];
        float* zp = Zg + ((size_t)b * C_ + o) * HW_ + n0 + tp;
        float4 v = { acc[0][j] + bb, acc[1][j] + bb, acc[2][j] + bb, acc[3][j] + bb };
        *(float4*)zp = v;
    }
}

// ---------------------------------------------------------------------------
// Kernel 5: GroupNorm stats (deterministic).
// ---------------------------------------------------------------------------
__global__ __launch_bounds__(256) void stats_kernel(
    const float* __restrict__ Zg, float* __restrict__ stats)
{
    const int t  = threadIdx.x;
    const int gr = blockIdx.x;
    const int b  = blockIdx.y;
    const float4* zp = (const float4*)(Zg + ((size_t)b * C_ + gr * 4) * HW_);
    float s = 0.f, ss = 0.f;
    for (int i = t; i < HW_; i += 256) {
        const float4 v = zp[i];
        s  += v.x + v.y + v.z + v.w;
        ss += v.x*v.x + v.y*v.y + v.z*v.z + v.w*v.w;
    }
    __shared__ float rs[256], rq[256];
    rs[t] = s; rq[t] = ss;
    __syncthreads();
    for (int off = 128; off > 0; off >>= 1) {
        if (t < off) { rs[t] += rs[t + off]; rq[t] += rq[t + off]; }
        __syncthreads();
    }
    if (t == 0) {
        const float invn = 1.0f / (4 * HW_);
        const float mean = rs[0] * invn;
        const float var  = rq[0] * invn - mean * mean;
        stats[((size_t)b * GROUPS_ + gr) * 2 + 0] = mean;
        stats[((size_t)b * GROUPS_ + gr) * 2 + 1] = rsqrtf(var + EPS_);
    }
}

// ---------------------------------------------------------------------------
// Kernel 6: normalize + affine + residual.
// ---------------------------------------------------------------------------
__global__ __launch_bounds__(256) void final_kernel(
    const float* __restrict__ Zg, const float* __restrict__ xg,
    const float* __restrict__ stats, const float* __restrict__ gnw,
    const float* __restrict__ gnb, float* __restrict__ out)
{
    const size_t i4  = (size_t)blockIdx.x * 256 + threadIdx.x;
    const size_t idx = i4 * 4;
    const int bc = (int)(i4 / (HW_ / 4));
    const int c  = bc & 127;
    const int b  = bc >> 7;
    const int g  = c >> 2;
    const float mean = stats[((size_t)b * GROUPS_ + g) * 2 + 0];
    const float rstd = stats[((size_t)b * GROUPS_ + g) * 2 + 1];
    const float sc = rstd * gnw[c];
    const float sh = gnb[c] - mean * sc;
    const float4 z  = *(const float4*)(Zg + idx);
    const float4 xv = *(const float4*)(xg + idx);
    float4 o;
    o.x = z.x * sc + sh + xv.x;
    o.y = z.y * sc + sh + xv.y;
    o.z = z.z * sc + sh + xv.z;
    o.w = z.w * sc + sh + xv.w;
    *(float4*)(out + idx) = o;
}

// ---------------------------------------------------------------------------
extern "C" void kernel_launch(void* const* d_in, const int* in_sizes, int n_in,
                              void* d_out, int out_size, void* d_ws, size_t ws_size,
                              hipStream_t stream)
{
    const float* x       = (const float*)d_in[0];
    const float* w_theta = (const float*)d_in[1];
    const float* b_theta = (const float*)d_in[2];
    const float* w_phi   = (const float*)d_in[3];
    const float* b_phi   = (const float*)d_in[4];
    const float* w_g     = (const float*)d_in[5];
    const float* b_g     = (const float*)d_in[6];
    const float* w_W     = (const float*)d_in[7];
    const float* b_W     = (const float*)d_in[8];
    const float* gn_w    = (const float*)d_in[9];
    const float* gn_b    = (const float*)d_in[10];
    float* out = (float*)d_out;
    char* wsb  = (char*)d_ws;

    // workspace layout (bytes)
    unsigned short* Q    = (unsigned short*)(wsb);             //  4,718,592
    unsigned short* K    = (unsigned short*)(wsb +  4718592);  //  1,179,648
    unsigned short* Vt   = (unsigned short*)(wsb +  5898240);  //  1,179,648
    unsigned short* phiF = (unsigned short*)(wsb +  7077888);  //  4,718,592
    unsigned short* gF   = (unsigned short*)(wsb + 11796480);  //  4,718,592
    float* Y             = (float*)(wsb +  7077888);           //  9,437,184 (aliases phiF+gF, dead after pool)
    float* Z             = (float*)(wsb + 16515072);           // 18,874,368
    float* stats         = (float*)(wsb + 35389440);           //  1 KB

    proj_kernel <<<dim3(HW_ / 32, B_, 3), 256, 0, stream>>>(
        x, w_theta, b_theta, w_phi, b_phi, w_g, b_g, Q, phiF, gF);
    pool_kernel <<<dim3(NP_ * CI_ / 256, B_, 2), 256, 0, stream>>>(phiF, gF, K, Vt);
    attn_kernel <<<dim3(HW_ / 32, B_), 64, 0, stream>>>(Q, K, Vt, Y);
    conv2_kernel<<<dim3(HW_ / 64, B_), 256, 0, stream>>>(Y, w_W, b_W, Z);
    stats_kernel<<<dim3(GROUPS_, B_), 256, 0, stream>>>(Z, stats);
    final_kernel<<<dim3((B_ * C_ * HW_) / 1024, 1), 256, 0, stream>>>(
        Z, x, stats, gn_w, gn_b, out);
}